// Round 7
// baseline (148.600 us; speedup 1.0000x reference)
//
#include <hip/hip_runtime.h>

#define NN 100
#define CC 32
#define HEE 32
#define FF 64
#define TILE 10
#define ROWS 7   // rows per wave in k_layer
#define STRIP 25 // rows per block in k_layer

// ---------------- K1: hi = x@ew1[:C]+eb1, hj = x@ew1[C:], d0 ----------------
__global__ __launch_bounds__(64) void k_hidden(
    const float* __restrict__ x, const float* __restrict__ A,
    const float* __restrict__ ew1, const float* __restrict__ eb1,
    float* __restrict__ hi, float* __restrict__ hj, float* __restrict__ d0) {
  int bn = blockIdx.x;
  int t = threadIdx.x;
  __shared__ float xr[CC];
  if (t < CC) xr[t] = x[bn * CC + t];

  const float* arow = A + (size_t)bn * NN;
  float s = 0.f;
  for (int j = t; j < NN; j += 64) s += arow[j];
#pragma unroll
  for (int off = 32; off > 0; off >>= 1) s += __shfl_down(s, off);
  if (t == 0) d0[bn] = 1.0f / sqrtf(s + 1.0f + 1e-5f);

  __syncthreads();
  int k = t & 31;
  const float* w = ew1 + (t < 32 ? 0 : CC * HEE) + k;
  float acc = (t < 32) ? eb1[k] : 0.f;
#pragma unroll
  for (int c = 0; c < CC; ++c) acc += xr[c] * w[c * HEE];
  if (t < 32) hi[bn * HEE + k] = acc;
  else        hj[bn * HEE + k] = acc;
}

// ---------------- K2: Ahat1 = A_pred + I, d1 ----------------
__global__ __launch_bounds__(256) void k_edge(
    const float* __restrict__ hi, const float* __restrict__ hj,
    const float* __restrict__ ew2, const float* __restrict__ eb2,
    const float* __restrict__ mask,
    float* __restrict__ Ahat1, float* __restrict__ d1) {
  __shared__ __align__(16) float shi[NN * HEE];
  __shared__ __align__(16) float shj[NN * HEE];
  __shared__ __align__(16) float sw2[HEE];
  __shared__ float sm[NN];
  __shared__ float sA[TILE][NN];
  int t = threadIdx.x;
  int b = blockIdx.x / 10;
  int i0 = (blockIdx.x % 10) * TILE;

  const float4* hi4 = (const float4*)(hi + (size_t)b * NN * HEE);
  const float4* hj4 = (const float4*)(hj + (size_t)b * NN * HEE);
  float4* shi4 = (float4*)shi;
  float4* shj4 = (float4*)shj;
  for (int v = t; v < NN * 8; v += 256) {
    int j = v >> 3, k4 = v & 7;
    int sw = (j << 3) | (k4 ^ (j & 7));
    shi4[sw] = hi4[v];
    shj4[sw] = hj4[v];
  }
  if (t < HEE) sw2[t] = ew2[t];
  if (t < NN) sm[t] = mask[b * NN + t];
  __syncthreads();

  float e2 = eb2[0];
  float4* sw24 = (float4*)sw2;
  for (int p = t; p < TILE * NN; p += 256) {
    int r = p / NN, j = p % NN, i = i0 + r;
    float val;
    if (j == i) {
      val = 1.0f;
    } else {
      float a1 = 0.f, a2 = 0.f;
#pragma unroll
      for (int k4 = 0; k4 < 8; ++k4) {
        float4 hii = shi4[(i << 3) | (k4 ^ (i & 7))];
        float4 hji = shj4[(i << 3) | (k4 ^ (i & 7))];
        float4 hij = shi4[(j << 3) | (k4 ^ (j & 7))];
        float4 hjj = shj4[(j << 3) | (k4 ^ (j & 7))];
        float4 w4 = sw24[k4];
        a1 += fmaxf(hii.x + hjj.x, 0.f) * w4.x;
        a2 += fmaxf(hij.x + hji.x, 0.f) * w4.x;
        a1 += fmaxf(hii.y + hjj.y, 0.f) * w4.y;
        a2 += fmaxf(hij.y + hji.y, 0.f) * w4.y;
        a1 += fmaxf(hii.z + hjj.z, 0.f) * w4.z;
        a2 += fmaxf(hij.z + hji.z, 0.f) * w4.z;
        a1 += fmaxf(hii.w + hjj.w, 0.f) * w4.w;
        a2 += fmaxf(hij.w + hji.w, 0.f) * w4.w;
      }
      val = expf(0.5f * (a1 + a2) + e2) * sm[i] * sm[j];
    }
    sA[r][j] = val;
    Ahat1[((size_t)b * NN + i) * NN + j] = val;
  }
  __syncthreads();
  if (t < TILE) {
    float s = 0.f;
    for (int j = 0; j < NN; ++j) s += sA[t][j];
    d1[b * NN + i0 + t] = 1.0f / sqrtf(s + 1e-5f);
  }
}

// ---------------- K_pre: P[b][rel][i][f] = sum_c x[b][i][c] * gw0[rel*32+c][f] ----------------
__global__ __launch_bounds__(256, 2) void k_pre2(
    const float* __restrict__ x, const float* __restrict__ gw0,
    float* __restrict__ P) {
  int t = threadIdx.x;
  int b = blockIdx.x & 127;
  int q = blockIdx.x >> 7;
  int wid = __builtin_amdgcn_readfirstlane(t >> 6);
  int lane = t & 63;
  int rg = wid * 4 + q;
  int row0 = rg * 8;
  if (row0 >= NN) return;

  int rowc[8];
#pragma unroll
  for (int r = 0; r < 8; ++r) rowc[r] = min(row0 + r, NN - 1);

  float acc0[8], acc1[8];
#pragma unroll
  for (int r = 0; r < 8; ++r) { acc0[r] = 0.f; acc1[r] = 0.f; }

  for (int c4 = 0; c4 < CC / 4; ++c4) {
    int c = c4 * 4;
    float w00 = gw0[(size_t)c * 64 + lane];
    float w01 = gw0[(size_t)(c + 1) * 64 + lane];
    float w02 = gw0[(size_t)(c + 2) * 64 + lane];
    float w03 = gw0[(size_t)(c + 3) * 64 + lane];
    float w10 = gw0[(size_t)(CC + c) * 64 + lane];
    float w11 = gw0[(size_t)(CC + c + 1) * 64 + lane];
    float w12 = gw0[(size_t)(CC + c + 2) * 64 + lane];
    float w13 = gw0[(size_t)(CC + c + 3) * 64 + lane];
#pragma unroll
    for (int r = 0; r < 8; ++r) {
      float4 a4 = *(const float4*)(x + ((size_t)b * NN + rowc[r]) * CC + c);
      acc0[r] += a4.x * w00 + a4.y * w01 + a4.z * w02 + a4.w * w03;
      acc1[r] += a4.x * w10 + a4.y * w11 + a4.z * w12 + a4.w * w13;
    }
  }
#pragma unroll
  for (int r = 0; r < 8; ++r) {
    int row = row0 + r;
    if (row < NN) {
      P[(((size_t)b * 2 + 0) * NN + row) * 64 + lane] = acc0[r];
      P[(((size_t)b * 2 + 1) * NN + row) * 64 + lane] = acc1[r];
    }
  }
}

// ---------------- K_layer ----------------
// grid B*4, 256 threads. sP (scaled P) in LDS; A/Ah rows read as UNIFORM global
// b128 loads (VMEM pipe, L1/L2-hot) via an opaque-VGPR-tainted base pointer so
// the compiler cannot prove uniformity (would emit s_load -> lgkmcnt collision
// with ds_read). LDS pipe now only carries 8 b32 sP reads per 56 FMAs.
template <int LAST>
__global__ __launch_bounds__(256, 2) void k_layer(
    const float* __restrict__ A, const float* __restrict__ Ah1,
    const float* __restrict__ d0, const float* __restrict__ d1,
    const float* __restrict__ mask, const float* __restrict__ Pin,
    const float* __restrict__ bias, const float* __restrict__ Wn,
    float* __restrict__ Pout) {
  __shared__ __align__(16) float sP[2][NN][64];        // 51.2 KB, scaled by d[j]
  __shared__ __align__(16) float srow[4][ROWS][64];    // 7.2 KB per-wave out rows
  int t = threadIdx.x;
  int b = blockIdx.x >> 2;
  int q = blockIdx.x & 3;
  int r0 = q * STRIP;

  // stage sP[rel][j][f] = P[b][rel][j][f] * d_rel[j]
  {
    const float4* P4 = (const float4*)(Pin + (size_t)b * 12800);
    float4* sP4 = (float4*)&sP[0][0][0];
    const float* d0b = d0 + b * NN;
    const float* d1b = d1 + b * NN;
    for (int v = t; v < 3200; v += 256) {
      int rel = (v >= 1600) ? 1 : 0;
      int rem = v - rel * 1600;
      int j = rem >> 4;
      float dv = rel ? d1b[j] : d0b[j];
      float4 p = P4[v];
      p.x *= dv; p.y *= dv; p.z *= dv; p.w *= dv;
      sP4[v] = p;
    }
  }
  __syncthreads();

  int wid = __builtin_amdgcn_readfirstlane(t >> 6);
  int lane = t & 63;
  int rw0 = wid * ROWS;  // 0,7,14,21

  int lr[ROWS];  // local row within strip (clamped -> duplicate rows benign)
#pragma unroll
  for (int r = 0; r < ROWS; ++r) lr[r] = min(rw0 + r, STRIP - 1);

  // opaque zero in a VGPR: defeats uniform-address analysis -> VMEM, not SMEM
  int vzero;
  asm volatile("v_mov_b32 %0, 0" : "=v"(vzero));

  const float* Arp[ROWS];
  const float* Ahp[ROWS];
#pragma unroll
  for (int r = 0; r < ROWS; ++r) {
    size_t rowoff = ((size_t)b * NN + (r0 + lr[r])) * NN;
    Arp[r] = A + rowoff + vzero;
    Ahp[r] = Ah1 + rowoff + vzero;
  }

  float acc0[ROWS], acc1[ROWS];
#pragma unroll
  for (int r = 0; r < ROWS; ++r) { acc0[r] = 0.f; acc1[r] = 0.f; }

  // ---- phase 1: A via uniform global b128 (vmcnt), sP via LDS b32 (lgkmcnt) ----
#pragma unroll 5
  for (int j4 = 0; j4 < NN / 4; ++j4) {
    int j = j4 * 4;
    float cp0[4], cp1[4];
#pragma unroll
    for (int u = 0; u < 4; ++u) { cp0[u] = sP[0][j + u][lane]; cp1[u] = sP[1][j + u][lane]; }
#pragma unroll
    for (int r = 0; r < ROWS; ++r) {
      float4 a0 = *(const float4*)(Arp[r] + j);  // uniform addr -> 16B L1 broadcast
      float4 a1 = *(const float4*)(Ahp[r] + j);
      acc0[r] += a0.x * cp0[0] + a0.y * cp0[1] + a0.z * cp0[2] + a0.w * cp0[3];
      acc1[r] += a1.x * cp1[0] + a1.y * cp1[1] + a1.z * cp1[2] + a1.w * cp1[3];
    }
  }

  float vb = bias[lane];
  const float* d0b = d0 + b * NN;
  const float* d1b = d1 + b * NN;
  const float* mb = mask + b * NN;
  float outv[ROWS];
#pragma unroll
  for (int r = 0; r < ROWS; ++r) {
    int gr = r0 + lr[r];
    float d0r = d0b[gr];
    float d1r = d1b[gr];
    float mr = mb[gr];
    float pdiag = sP[0][gr][lane];  // Pd0[row][lane]  (+I term of rel0)
    float v = (acc0[r] + pdiag) * d0r + acc1[r] * d1r;
    v = (v + vb) * mr;
    outv[r] = fmaxf(v, 0.f);
  }

  if (LAST) {
    float mx = outv[0];
#pragma unroll
    for (int r = 1; r < ROWS; ++r) mx = fmaxf(mx, outv[r]);
    Pout[((size_t)b * 16 + q * 4 + wid) * 64 + lane] = mx;
    return;
  }

  // ---- phase 2: P_next = out @ Wn (srow wave-private; W per-lane loads = vmcnt) ----
#pragma unroll
  for (int r = 0; r < ROWS; ++r) srow[wid][r][lane] = outv[r];

  float pacc0[ROWS], pacc1[ROWS];
#pragma unroll
  for (int r = 0; r < ROWS; ++r) { pacc0[r] = 0.f; pacc1[r] = 0.f; }

#pragma unroll 4
  for (int k4 = 0; k4 < 16; ++k4) {
    int k = k4 * 4;
    float w00 = Wn[(size_t)k * 64 + lane];
    float w01 = Wn[(size_t)(k + 1) * 64 + lane];
    float w02 = Wn[(size_t)(k + 2) * 64 + lane];
    float w03 = Wn[(size_t)(k + 3) * 64 + lane];
    float w10 = Wn[(size_t)(64 + k) * 64 + lane];
    float w11 = Wn[(size_t)(64 + k + 1) * 64 + lane];
    float w12 = Wn[(size_t)(64 + k + 2) * 64 + lane];
    float w13 = Wn[(size_t)(64 + k + 3) * 64 + lane];
#pragma unroll
    for (int r = 0; r < ROWS; ++r) {
      float4 s4 = *(const float4*)&srow[wid][r][k];  // broadcast read
      pacc0[r] += s4.x * w00 + s4.y * w01 + s4.z * w02 + s4.w * w03;
      pacc1[r] += s4.x * w10 + s4.y * w11 + s4.z * w12 + s4.w * w13;
    }
  }
#pragma unroll
  for (int r = 0; r < ROWS; ++r) {
    int row = r0 + lr[r];
    Pout[(((size_t)b * 2 + 0) * NN + row) * 64 + lane] = pacc0[r];
    Pout[(((size_t)b * 2 + 1) * NN + row) * 64 + lane] = pacc1[r];
  }
}

// ---------------- K_final: max over 16 rowgroup partials + classifier ----------------
__global__ __launch_bounds__(64) void k_final(
    const float* __restrict__ pooled, const float* __restrict__ fw,
    const float* __restrict__ fb, float* __restrict__ out) {
  int b = blockIdx.x;
  int t = threadIdx.x;
  __shared__ float sp[FF];
  float m = -3.402823466e38f;
  const float* pb = pooled + (size_t)b * 16 * 64;
#pragma unroll
  for (int rg = 0; rg < 16; ++rg) m = fmaxf(m, pb[rg * 64 + t]);
  sp[t] = m;
  __syncthreads();
  if (t < 16) {
    float acc = fb[t];
#pragma unroll
    for (int f = 0; f < FF; ++f) acc += sp[f] * fw[f * 16 + t];
    out[b * 16 + t] = acc;
  }
}

extern "C" void kernel_launch(void* const* d_in, const int* in_sizes, int n_in,
                              void* d_out, int out_size, void* d_ws, size_t ws_size,
                              hipStream_t stream) {
  const float* x    = (const float*)d_in[0];
  const float* A    = (const float*)d_in[1];
  const float* mask = (const float*)d_in[2];
  const float* ew1  = (const float*)d_in[3];
  const float* eb1  = (const float*)d_in[4];
  const float* ew2  = (const float*)d_in[5];
  const float* eb2  = (const float*)d_in[6];
  const float* gw0  = (const float*)d_in[7];
  const float* gb0  = (const float*)d_in[8];
  const float* gw1  = (const float*)d_in[9];
  const float* gb1  = (const float*)d_in[10];
  const float* gw2  = (const float*)d_in[11];
  const float* gb2  = (const float*)d_in[12];
  const float* fw   = (const float*)d_in[13];
  const float* fb   = (const float*)d_in[14];
  float* out = (float*)d_out;
  float* ws = (float*)d_ws;

  const int B = 128;
  float* hi  = ws;                   // 409600
  float* hj  = hi + 409600;          // 409600
  float* Ah1 = hj + 409600;          // 1280000
  float* d0  = Ah1 + 1280000;        // 12800
  float* d1  = d0 + 12800;           // 12800
  float* Pa  = d1 + 12800;           // 1638400  [B][2][100][64]
  float* Pb  = Pa + 1638400;         // 1638400
  float* pooled = Pb + 1638400;      // 128*16*64 = 131072

  k_hidden<<<B * NN, 64, 0, stream>>>(x, A, ew1, eb1, hi, hj, d0);
  k_edge<<<B * 10, 256, 0, stream>>>(hi, hj, ew2, eb2, mask, Ah1, d1);
  k_pre2<<<512, 256, 0, stream>>>(x, gw0, Pa);
  k_layer<0><<<B * 4, 256, 0, stream>>>(A, Ah1, d0, d1, mask, Pa, gb0, gw1, Pb);
  k_layer<0><<<B * 4, 256, 0, stream>>>(A, Ah1, d0, d1, mask, Pb, gb1, gw2, Pa);
  k_layer<1><<<B * 4, 256, 0, stream>>>(A, Ah1, d0, d1, mask, Pa, gb2, gw2, pooled);
  k_final<<<B, 64, 0, stream>>>(pooled, fw, fb, out);
}

// Round 8
// 92.608 us; speedup vs baseline: 1.6046x; 1.6046x over previous
//
#include <hip/hip_runtime.h>

#define NN 100
#define CC 32
#define HEE 32
#define FF 64
#define TILE 10

typedef float f32x4 __attribute__((ext_vector_type(4)));
typedef __bf16 bf16x8 __attribute__((ext_vector_type(8)));
#define MFMA16 __builtin_amdgcn_mfma_f32_16x16x32_bf16

union FragU {
  unsigned short s[8];
  bf16x8 v;
  float4 f4;
};

// round-to-nearest-even bf16 split: v ~= hi + lo (hi,lo bf16 bit patterns)
static __device__ __forceinline__ void split2(float v, unsigned short& h, unsigned short& l) {
  union { float f; unsigned u; } c; c.f = v;
  unsigned r = c.u + 0x7FFF + ((c.u >> 16) & 1);
  unsigned short hs = (unsigned short)(r >> 16);
  union { unsigned u; float f; } hb; hb.u = ((unsigned)hs) << 16;
  float rem = v - hb.f;
  union { float f; unsigned u; } c2; c2.f = rem;
  unsigned r2 = c2.u + 0x7FFF + ((c2.u >> 16) & 1);
  h = hs; l = (unsigned short)(r2 >> 16);
}

// ---------------- K1: hi = x@ew1[:C]+eb1, hj = x@ew1[C:], d0 ----------------
__global__ __launch_bounds__(64) void k_hidden(
    const float* __restrict__ x, const float* __restrict__ A,
    const float* __restrict__ ew1, const float* __restrict__ eb1,
    float* __restrict__ hi, float* __restrict__ hj, float* __restrict__ d0) {
  int bn = blockIdx.x;
  int t = threadIdx.x;
  __shared__ float xr[CC];
  if (t < CC) xr[t] = x[bn * CC + t];

  const float* arow = A + (size_t)bn * NN;
  float s = 0.f;
  for (int j = t; j < NN; j += 64) s += arow[j];
#pragma unroll
  for (int off = 32; off > 0; off >>= 1) s += __shfl_down(s, off);
  if (t == 0) d0[bn] = 1.0f / sqrtf(s + 1.0f + 1e-5f);

  __syncthreads();
  int k = t & 31;
  const float* w = ew1 + (t < 32 ? 0 : CC * HEE) + k;
  float acc = (t < 32) ? eb1[k] : 0.f;
#pragma unroll
  for (int c = 0; c < CC; ++c) acc += xr[c] * w[c * HEE];
  if (t < 32) hi[bn * HEE + k] = acc;
  else        hj[bn * HEE + k] = acc;
}

// ---------------- K2: Ahat1 = A_pred + I, d1 ----------------
__global__ __launch_bounds__(256) void k_edge(
    const float* __restrict__ hi, const float* __restrict__ hj,
    const float* __restrict__ ew2, const float* __restrict__ eb2,
    const float* __restrict__ mask,
    float* __restrict__ Ahat1, float* __restrict__ d1) {
  __shared__ __align__(16) float shi[NN * HEE];
  __shared__ __align__(16) float shj[NN * HEE];
  __shared__ __align__(16) float sw2[HEE];
  __shared__ float sm[NN];
  __shared__ float sA[TILE][NN];
  int t = threadIdx.x;
  int b = blockIdx.x / 10;
  int i0 = (blockIdx.x % 10) * TILE;

  const float4* hi4 = (const float4*)(hi + (size_t)b * NN * HEE);
  const float4* hj4 = (const float4*)(hj + (size_t)b * NN * HEE);
  float4* shi4 = (float4*)shi;
  float4* shj4 = (float4*)shj;
  for (int v = t; v < NN * 8; v += 256) {
    int j = v >> 3, k4 = v & 7;
    int sw = (j << 3) | (k4 ^ (j & 7));
    shi4[sw] = hi4[v];
    shj4[sw] = hj4[v];
  }
  if (t < HEE) sw2[t] = ew2[t];
  if (t < NN) sm[t] = mask[b * NN + t];
  __syncthreads();

  float e2 = eb2[0];
  float4* sw24 = (float4*)sw2;
  for (int p = t; p < TILE * NN; p += 256) {
    int r = p / NN, j = p % NN, i = i0 + r;
    float val;
    if (j == i) {
      val = 1.0f;
    } else {
      float a1 = 0.f, a2 = 0.f;
#pragma unroll
      for (int k4 = 0; k4 < 8; ++k4) {
        float4 hii = shi4[(i << 3) | (k4 ^ (i & 7))];
        float4 hji = shj4[(i << 3) | (k4 ^ (i & 7))];
        float4 hij = shi4[(j << 3) | (k4 ^ (j & 7))];
        float4 hjj = shj4[(j << 3) | (k4 ^ (j & 7))];
        float4 w4 = sw24[k4];
        a1 += fmaxf(hii.x + hjj.x, 0.f) * w4.x;
        a2 += fmaxf(hij.x + hji.x, 0.f) * w4.x;
        a1 += fmaxf(hii.y + hjj.y, 0.f) * w4.y;
        a2 += fmaxf(hij.y + hji.y, 0.f) * w4.y;
        a1 += fmaxf(hii.z + hjj.z, 0.f) * w4.z;
        a2 += fmaxf(hij.z + hji.z, 0.f) * w4.z;
        a1 += fmaxf(hii.w + hjj.w, 0.f) * w4.w;
        a2 += fmaxf(hij.w + hji.w, 0.f) * w4.w;
      }
      val = expf(0.5f * (a1 + a2) + e2) * sm[i] * sm[j];
    }
    sA[r][j] = val;
    Ahat1[((size_t)b * NN + i) * NN + j] = val;
  }
  __syncthreads();
  if (t < TILE) {
    float s = 0.f;
    for (int j = 0; j < NN; ++j) s += sA[t][j];
    d1[b * NN + i0 + t] = 1.0f / sqrtf(s + 1e-5f);
  }
}

// ---------------- k_fmtL: L fragment image (A-operand), split bf16 ----------------
// L[i][k]: k in [0,128): rel0 j=k: d0_i*(A+I)*d0_j; k in [128,256): rel1 j=k-128: d1*Ahat1*d1.
// Frag layout per (b,mt,kt): lane: m = mt*16+(lane&15), k = kt*32 + (lane>>4)*8 + e.
// Image: frag = (b*7+mt)*8+kt; bytes: frag*2048 + lane*16 (hi), +1024 (lo).
__global__ __launch_bounds__(256) void k_fmtL(
    const float* __restrict__ A, const float* __restrict__ Ahat1,
    const float* __restrict__ d0, const float* __restrict__ d1,
    float* __restrict__ Limg) {
  int gid = blockIdx.x * 256 + threadIdx.x;
  int lane = gid & 63;
  int frag = gid >> 6;           // 0 .. 128*56-1
  int b = frag / 56;
  int r = frag % 56;
  int mt = r >> 3, kt = r & 7;
  int m = mt * 16 + (lane & 15);
  int o = lane >> 4;
  int rel = kt >> 2;
  int jb = (kt & 3) * 32 + o * 8;

  float v[8];
  if (m < NN) {
    if (rel == 0) {
      float di = d0[b * NN + m];
      const float* Ar = A + ((size_t)b * NN + m) * NN;
#pragma unroll
      for (int e = 0; e < 8; ++e) {
        int j = jb + e;
        v[e] = (j < NN) ? di * (Ar[j] + (j == m ? 1.f : 0.f)) * d0[b * NN + j] : 0.f;
      }
    } else {
      float di = d1[b * NN + m];
      const float* Ar = Ahat1 + ((size_t)b * NN + m) * NN;
#pragma unroll
      for (int e = 0; e < 8; ++e) {
        int j = jb + e;
        v[e] = (j < NN) ? di * Ar[j] * d1[b * NN + j] : 0.f;
      }
    }
  } else {
#pragma unroll
    for (int e = 0; e < 8; ++e) v[e] = 0.f;
  }
  FragU hh, ll;
#pragma unroll
  for (int e = 0; e < 8; ++e) split2(v[e], hh.s[e], ll.s[e]);
  char* dst = (char*)Limg + (size_t)frag * 2048 + lane * 16;
  *(float4*)dst = hh.f4;
  *(float4*)(dst + 1024) = ll.f4;
}

// ---------------- k_fmtW: W fragment images (B-operand) for gw1, gw2 ----------------
// B[k][n]: k in [0,64), n = rel*64+f: value = W[rel*64+k][f]. Frags: kt2 in 2, nt2 in 8.
__global__ __launch_bounds__(256) void k_fmtW(
    const float* __restrict__ gw1, const float* __restrict__ gw2,
    float* __restrict__ Wimg) {
  int gid = blockIdx.x * 256 + threadIdx.x;
  int lane = gid & 63;
  int frag = gid >> 6;  // 0..31
  int wsel = frag >> 4;
  int rr = frag & 15;
  int kt2 = rr >> 3, nt2 = rr & 7;
  int n = nt2 * 16 + (lane & 15);
  int rel = n >> 6, f = n & 63;
  int kb = kt2 * 32 + (lane >> 4) * 8;
  const float* W = wsel ? gw2 : gw1;
  FragU hh, ll;
#pragma unroll
  for (int e = 0; e < 8; ++e) {
    float v = W[(size_t)(rel * 64 + kb + e) * 64 + f];
    split2(v, hh.s[e], ll.s[e]);
  }
  char* dst = (char*)Wimg + (size_t)frag * 2048 + lane * 16;
  *(float4*)dst = hh.f4;
  *(float4*)(dst + 1024) = ll.f4;
}

// ---------------- k_preP: P0 = x@gw0, written as P fragment image (B-operand) ----------------
// P image per b: frag (kt in 8, nt in 4): lane: k = kt*32+(lane>>4)*8+e (k = rel*128 + i), n = nt*16+(lane&15) = f.
__global__ __launch_bounds__(256, 2) void k_preP(
    const float* __restrict__ x, const float* __restrict__ gw0,
    float* __restrict__ Pimg) {
  int t = threadIdx.x;
  int b = blockIdx.x & 127;
  int q = blockIdx.x >> 7;
  int wid = __builtin_amdgcn_readfirstlane(t >> 6);
  int lane = t & 63;
  int rg = wid * 4 + q;
  int row0 = rg * 8;
  if (row0 >= NN) return;

  int rowc[8];
#pragma unroll
  for (int r = 0; r < 8; ++r) rowc[r] = min(row0 + r, NN - 1);

  float acc0[8], acc1[8];
#pragma unroll
  for (int r = 0; r < 8; ++r) { acc0[r] = 0.f; acc1[r] = 0.f; }

  for (int c4 = 0; c4 < CC / 4; ++c4) {
    int c = c4 * 4;
    float w00 = gw0[(size_t)c * 64 + lane];
    float w01 = gw0[(size_t)(c + 1) * 64 + lane];
    float w02 = gw0[(size_t)(c + 2) * 64 + lane];
    float w03 = gw0[(size_t)(c + 3) * 64 + lane];
    float w10 = gw0[(size_t)(CC + c) * 64 + lane];
    float w11 = gw0[(size_t)(CC + c + 1) * 64 + lane];
    float w12 = gw0[(size_t)(CC + c + 2) * 64 + lane];
    float w13 = gw0[(size_t)(CC + c + 3) * 64 + lane];
#pragma unroll
    for (int r = 0; r < 8; ++r) {
      float4 a4 = *(const float4*)(x + ((size_t)b * NN + rowc[r]) * CC + c);
      acc0[r] += a4.x * w00 + a4.y * w01 + a4.z * w02 + a4.w * w03;
      acc1[r] += a4.x * w10 + a4.y * w11 + a4.z * w12 + a4.w * w13;
    }
  }
  // zero pad rows >= 100, then emit image frags (e index = r since row0 is 8-aligned)
#pragma unroll
  for (int r = 0; r < 8; ++r) {
    if (row0 + r >= NN) { acc0[r] = 0.f; acc1[r] = 0.f; }
  }
  int o_t = (row0 & 31) >> 3;
  int lane_t = o_t * 16 + (lane & 15);
  int nt_t = lane >> 4;
  FragU h0, l0, h1, l1;
#pragma unroll
  for (int r = 0; r < 8; ++r) {
    split2(acc0[r], h0.s[r], l0.s[r]);
    split2(acc1[r], h1.s[r], l1.s[r]);
  }
  char* base = (char*)Pimg + (size_t)b * 65536;
  int kt0 = row0 >> 5;
  char* dp0 = base + (size_t)(kt0 * 4 + nt_t) * 2048 + lane_t * 16;
  *(float4*)dp0 = h0.f4;
  *(float4*)(dp0 + 1024) = l0.f4;
  char* dp1 = base + (size_t)((4 + kt0) * 4 + nt_t) * 2048 + lane_t * 16;
  *(float4*)dp1 = h1.f4;
  *(float4*)(dp1 + 1024) = l1.f4;
}

// ---------------- k_gmm1: out = relu((L@P + bias)*mask)  [MFMA] ----------------
// grid 512 = (b, q): q = h*2+np. 4 waves: wave w -> nt = np*2+(w&1), mt pair = h*3+(w>>1)*2+{0,1}.
// LAST=1: pooled partial max into pooled[b][h][f] (f-halves disjoint across np).
template <int LAST>
__global__ __launch_bounds__(256, 2) void k_gmm1(
    const float* __restrict__ Limg, const float* __restrict__ Pimg,
    const float* __restrict__ bias, const float* __restrict__ mask,
    float* __restrict__ outbuf, float* __restrict__ pooled) {
  __shared__ float pm[4][16];
  int t = threadIdx.x;
  int b = blockIdx.x >> 2;
  int q = blockIdx.x & 3;
  int h = q >> 1, np = q & 1;
  int w = __builtin_amdgcn_readfirstlane(t >> 6);
  int lane = t & 63;
  int nt = np * 2 + (w & 1);
  int mt0 = h * 3 + (w >> 1) * 2;
  int mt1 = mt0 + 1;

  const char* Lb = (const char*)Limg + (size_t)b * 114688;
  const char* Pb = (const char*)Pimg + (size_t)b * 65536;

  f32x4 acc0 = {0.f, 0.f, 0.f, 0.f};
  f32x4 acc1 = {0.f, 0.f, 0.f, 0.f};
#pragma unroll
  for (int kt = 0; kt < 8; ++kt) {
    FragU bh, bl, a0h, a0l, a1h, a1l;
    const char* pp = Pb + (size_t)(kt * 4 + nt) * 2048 + lane * 16;
    bh.f4 = *(const float4*)pp;
    bl.f4 = *(const float4*)(pp + 1024);
    const char* l0p = Lb + (size_t)(mt0 * 8 + kt) * 2048 + lane * 16;
    const char* l1p = Lb + (size_t)(mt1 * 8 + kt) * 2048 + lane * 16;
    a0h.f4 = *(const float4*)l0p;
    a0l.f4 = *(const float4*)(l0p + 1024);
    a1h.f4 = *(const float4*)l1p;
    a1l.f4 = *(const float4*)(l1p + 1024);
    acc0 = MFMA16(a0h.v, bh.v, acc0, 0, 0, 0);
    acc1 = MFMA16(a1h.v, bh.v, acc1, 0, 0, 0);
    acc0 = MFMA16(a0l.v, bh.v, acc0, 0, 0, 0);
    acc1 = MFMA16(a1l.v, bh.v, acc1, 0, 0, 0);
    acc0 = MFMA16(a0h.v, bl.v, acc0, 0, 0, 0);
    acc1 = MFMA16(a1h.v, bl.v, acc1, 0, 0, 0);
  }

  int f = nt * 16 + (lane & 15);
  float biasf = bias[f];
  const float* mb = mask + b * NN;
  int rbase = (lane >> 4) * 4;
  float mx = 0.f;

#pragma unroll
  for (int reg = 0; reg < 4; ++reg) {
    int gi = mt0 * 16 + rbase + reg;
    float v = 0.f;
    if (gi < NN) v = fmaxf((acc0[reg] + biasf) * mb[gi], 0.f);
    if (!LAST) outbuf[((size_t)b * 112 + gi) * 64 + f] = v;
    else mx = fmaxf(mx, v);
  }
#pragma unroll
  for (int reg = 0; reg < 4; ++reg) {
    int gi = mt1 * 16 + rbase + reg;
    float v = 0.f;
    if (gi < NN) v = fmaxf((acc1[reg] + biasf) * mb[gi], 0.f);
    if (!LAST) outbuf[((size_t)b * 112 + gi) * 64 + f] = v;
    else mx = fmaxf(mx, v);
  }

  if (LAST) {
    mx = fmaxf(mx, __shfl_xor(mx, 16));
    mx = fmaxf(mx, __shfl_xor(mx, 32));
    if (lane < 16) pm[w][lane] = mx;
    __syncthreads();
    if (w < 2 && lane < 16) {
      float m2 = fmaxf(pm[w][lane], pm[w + 2][lane]);
      pooled[((size_t)b * 2 + h) * 64 + (np * 2 + w) * 16 + lane] = m2;
    }
  }
}

// ---------------- k_gmm2: P_next = out @ Wcat, emitted as next P-image ----------------
// grid 512 = (b, q2): h = q2>>1, nh = q2&1. wave w -> nt2 = nh*4+w; 4 mt tiles = h*3+l.
__global__ __launch_bounds__(256, 2) void k_gmm2(
    const float* __restrict__ outbuf, const float* __restrict__ Wimg,
    float* __restrict__ Pimg_out) {
  int t = threadIdx.x;
  int b = blockIdx.x >> 2;
  int q2 = blockIdx.x & 3;
  int h = q2 >> 1, nh = q2 & 1;
  int w = __builtin_amdgcn_readfirstlane(t >> 6);
  int lane = t & 63;
  int nt2 = nh * 4 + w;
  int o = lane >> 4;
  int ml = lane & 15;

  f32x4 acc[4];
#pragma unroll
  for (int l = 0; l < 4; ++l) acc[l] = (f32x4){0.f, 0.f, 0.f, 0.f};

#pragma unroll
  for (int kt2 = 0; kt2 < 2; ++kt2) {
    FragU bh, bl;
    const char* wp = (const char*)Wimg + (size_t)(kt2 * 8 + nt2) * 2048 + lane * 16;
    bh.f4 = *(const float4*)wp;
    bl.f4 = *(const float4*)(wp + 1024);
    int kb = kt2 * 32 + o * 8;
#pragma unroll
    for (int l = 0; l < 4; ++l) {
      int m = (h * 3 + l) * 16 + ml;
      const float* op = outbuf + ((size_t)b * 112 + m) * 64 + kb;
      float4 v0 = *(const float4*)op;
      float4 v1 = *(const float4*)(op + 4);
      float vv[8] = {v0.x, v0.y, v0.z, v0.w, v1.x, v1.y, v1.z, v1.w};
      FragU ah, al;
#pragma unroll
      for (int e = 0; e < 8; ++e) split2(vv[e], ah.s[e], al.s[e]);
      acc[l] = MFMA16(ah.v, bh.v, acc[l], 0, 0, 0);
      acc[l] = MFMA16(al.v, bh.v, acc[l], 0, 0, 0);
      acc[l] = MFMA16(ah.v, bl.v, acc[l], 0, 0, 0);
    }
  }

  int nprime = nt2 * 16 + ml;
  int rel = nprime >> 6;
  int f = nprime & 63;
  int nt_t = f >> 4;
  char* Pout = (char*)Pimg_out + (size_t)b * 65536;
#pragma unroll
  for (int l = 0; l < 4; ++l) {
    int i0 = (h * 3 + l) * 16 + (lane >> 4) * 4;
    int kt_ = (rel * 128 + i0) >> 5;
    int o_t = ((rel * 128 + i0) & 31) >> 3;
    int e0 = i0 & 7;  // 0 or 4
    unsigned short hs[4], ls[4];
#pragma unroll
    for (int reg = 0; reg < 4; ++reg) split2(acc[l][reg], hs[reg], ls[reg]);
    ushort4 hv = {hs[0], hs[1], hs[2], hs[3]};
    ushort4 lv = {ls[0], ls[1], ls[2], ls[3]};
    char* dst = Pout + (size_t)(kt_ * 4 + nt_t) * 2048 + (o_t * 16 + (f & 15)) * 16 + e0 * 2;
    *(ushort4*)dst = hv;
    *(ushort4*)(dst + 1024) = lv;
  }
}

// ---------------- k_final: combine 2 pooled halves + classifier ----------------
__global__ __launch_bounds__(64) void k_final(
    const float* __restrict__ pooled, const float* __restrict__ fw,
    const float* __restrict__ fb, float* __restrict__ out) {
  int b = blockIdx.x;
  int t = threadIdx.x;
  __shared__ float sp[FF];
  float m = fmaxf(pooled[(size_t)b * 128 + t], pooled[(size_t)b * 128 + 64 + t]);
  sp[t] = m;
  __syncthreads();
  if (t < 16) {
    float acc = fb[t];
#pragma unroll
    for (int f = 0; f < FF; ++f) acc += sp[f] * fw[f * 16 + t];
    out[b * 16 + t] = acc;
  }
}

extern "C" void kernel_launch(void* const* d_in, const int* in_sizes, int n_in,
                              void* d_out, int out_size, void* d_ws, size_t ws_size,
                              hipStream_t stream) {
  const float* x    = (const float*)d_in[0];
  const float* A    = (const float*)d_in[1];
  const float* mask = (const float*)d_in[2];
  const float* ew1  = (const float*)d_in[3];
  const float* eb1  = (const float*)d_in[4];
  const float* ew2  = (const float*)d_in[5];
  const float* eb2  = (const float*)d_in[6];
  const float* gw0  = (const float*)d_in[7];
  const float* gb0  = (const float*)d_in[8];
  const float* gw1  = (const float*)d_in[9];
  const float* gb1  = (const float*)d_in[10];
  const float* gw2  = (const float*)d_in[11];
  const float* gb2  = (const float*)d_in[12];
  const float* fw   = (const float*)d_in[13];
  const float* fb   = (const float*)d_in[14];
  float* out = (float*)d_out;
  float* ws = (float*)d_ws;

  const int B = 128;
  float* hi   = ws;                      // 409600
  float* hj   = hi + 409600;             // 409600
  float* Ah1  = hj + 409600;             // 1280000
  float* d0   = Ah1 + 1280000;           // 12800
  float* d1   = d0 + 12800;              // 12800
  float* Limg = d1 + 12800;              // 3670016 f (128*56*2048 B)
  float* PA   = Limg + 3670016;          // 2097152 f (128*32*2048 B)
  float* PB   = PA + 2097152;            // 2097152 f
  float* Wimg = PB + 2097152;            // 16384 f (32*2048 B)
  float* outb = Wimg + 16384;            // 917504 f (128*112*64)
  float* pooled = outb + 917504;         // 128*2*64

  k_hidden<<<B * NN, 64, 0, stream>>>(x, A, ew1, eb1, hi, hj, d0);
  k_edge<<<B * 10, 256, 0, stream>>>(hi, hj, ew2, eb2, mask, Ah1, d1);
  k_fmtW<<<8, 256, 0, stream>>>(gw1, gw2, Wimg);
  k_preP<<<512, 256, 0, stream>>>(x, gw0, PA);
  k_fmtL<<<1792, 256, 0, stream>>>(A, Ah1, d0, d1, Limg);

  k_gmm1<0><<<512, 256, 0, stream>>>(Limg, PA, gb0, mask, outb, pooled);
  k_gmm2<<<512, 256, 0, stream>>>(outb, (const float*)Wimg, PB);            // wsel 0 (gw1)
  k_gmm1<0><<<512, 256, 0, stream>>>(Limg, PB, gb1, mask, outb, pooled);
  k_gmm2<<<512, 256, 0, stream>>>(outb, (const float*)((const char*)Wimg + 32768), PA);  // wsel 1 (gw2)
  k_gmm1<1><<<512, 256, 0, stream>>>(Limg, PA, gb2, mask, outb, pooled);

  k_final<<<B, 64, 0, stream>>>(pooled, fw, fb, out);
}